// Round 8
// baseline (1816.005 us; speedup 1.0000x reference)
//
#include <hip/hip_runtime.h>
#include <hip/hip_fp16.h>

// GPRPropagation: out = sum_k w_k * (D^-1/2 (A+I) D^-1/2)^k x, k=0..ORDER
// N=100000, F=128, E=1600000, ORDER=10.
//
// R6/R7 lesson: prop is line-fill-bound; each XCD pulled the whole 25.6MB
// hidden buffer through its 4MB L2 (FETCH ~210MB/round). R8: FEATURE-SLICED
// slabs. 8 slabs x 16 features (fp16, [g][node][16] = 3.2MB each), blocks
// with (blockIdx&7)==g process slab g only -> per-XCD random gather hits an
// L2-RESIDENT 3.2MB slab. State stored as z = D^-1/2 y so the gather is a
// pure unweighted sum (no per-edge dinv); dest-side: z_new = dinv^2*s + wj*xd,
// xd = dinv.*x. Edges read via nontemporal loads (streamed 8x, don't evict
// the slab). Build phase: R6-style (count/scan/8-group rescan place).

#define F 128
#define SCAN_B 256

__global__ void count_kernel(const int* __restrict__ ei, int E,
                             int* __restrict__ cnt) {
    int e = blockIdx.x * blockDim.x + threadIdx.x;
    if (e < E) {
        int c = ei[(size_t)E + e];   // col = destination
        atomicAdd(&cnt[c], 1);
    }
}

// scan1 + dinv fused
__global__ void scan1_kernel(const int* __restrict__ cnt, int* __restrict__ offs,
                             int* __restrict__ bsums, float* __restrict__ dinv,
                             int N) {
    __shared__ int sm[SCAN_B];
    int i = blockIdx.x * SCAN_B + threadIdx.x;
    int v = (i < N) ? cnt[i] : 0;
    if (i < N) dinv[i] = rsqrtf((float)(v + 1));  // + self loop
    sm[threadIdx.x] = v;
    __syncthreads();
    for (int d = 1; d < SCAN_B; d <<= 1) {
        int t = (threadIdx.x >= d) ? sm[threadIdx.x - d] : 0;
        __syncthreads();
        sm[threadIdx.x] += t;
        __syncthreads();
    }
    if (i < N) offs[i] = sm[threadIdx.x] - v;
    if (threadIdx.x == SCAN_B - 1) bsums[blockIdx.x] = sm[SCAN_B - 1];
}

__global__ void scan2_kernel(int* __restrict__ bsums, int nb) {
    __shared__ int sm[SCAN_B];
    __shared__ int carry;
    if (threadIdx.x == 0) carry = 0;
    __syncthreads();
    for (int base = 0; base < nb; base += SCAN_B) {
        int i = base + threadIdx.x;
        int v = (i < nb) ? bsums[i] : 0;
        sm[threadIdx.x] = v;
        __syncthreads();
        for (int d = 1; d < SCAN_B; d <<= 1) {
            int t = (threadIdx.x >= d) ? sm[threadIdx.x - d] : 0;
            __syncthreads();
            sm[threadIdx.x] += t;
            __syncthreads();
        }
        if (i < nb) bsums[i] = sm[threadIdx.x] - v + carry;
        __syncthreads();
        if (threadIdx.x == 0) carry += sm[SCAN_B - 1];
        __syncthreads();
    }
}

__global__ void scan3_kernel(int* __restrict__ offs, const int* __restrict__ bsums,
                             int* __restrict__ cursor, int N, int E) {
    int i = blockIdx.x * blockDim.x + threadIdx.x;
    if (i < N) {
        int o = offs[i] + bsums[i / SCAN_B];
        offs[i] = o;
        cursor[i] = o;
    }
    if (i == N) offs[N] = E;
}

// 8-group rescan place (R6): group g handles dst range [N*g/8, N*(g+1)/8);
// its CSR slice is contiguous -> XCD-local atomics + full-line writeback.
__global__ void place_kernel(const int* __restrict__ ei, int E,
                             int* __restrict__ cursor, int* __restrict__ edges,
                             int N) {
    const int g = blockIdx.x & 7;
    const int b = blockIdx.x >> 3;
    const int nb = gridDim.x >> 3;
    const int lo = (int)((long long)N * g / 8);
    const int hi = (int)((long long)N * (g + 1) / 8);
    const int stride = nb * blockDim.x;
    for (int e = b * blockDim.x + threadIdx.x; e < E; e += stride) {
        int c = ei[(size_t)E + e];
        if (c < lo || c >= hi) continue;
        int pos = atomicAdd(&cursor[c], 1);
        edges[pos] = ei[e];
    }
}

__device__ __forceinline__ unsigned pk(float a, float b) {
    __half2 h = __floats2half2_rn(a, b);
    return *(unsigned*)&h;
}

// Seed: xd = fp16(dinv.*x), z = fp16(w[order]*dinv.*x), in slab layout
// [g][node][16 halfs] = 2 uint4 per (g,node). g = blockIdx&7 primes XCD g's L2.
__global__ __launch_bounds__(256) void conv_kernel(
    const float* __restrict__ x, const float* __restrict__ dinv,
    uint4* __restrict__ xd, uint4* __restrict__ z,
    const float* __restrict__ wts, int order, int N) {
    const int g = blockIdx.x & 7;
    const int c = (blockIdx.x >> 3) * blockDim.x + threadIdx.x;
    if (c >= N) return;
    const float dc = dinv[c];
    const float wl = wts[order] * dc;
    const float4* xr = (const float4*)(x + (size_t)c * F + g * 16);
    float4 a = xr[0], b = xr[1], d = xr[2], e = xr[3];
    size_t off = ((size_t)g * N + c) * 2;
    uint4 u0, u1;
    u0.x = pk(dc * a.x, dc * a.y);  u0.y = pk(dc * a.z, dc * a.w);
    u0.z = pk(dc * b.x, dc * b.y);  u0.w = pk(dc * b.z, dc * b.w);
    u1.x = pk(dc * d.x, dc * d.y);  u1.y = pk(dc * d.z, dc * d.w);
    u1.z = pk(dc * e.x, dc * e.y);  u1.w = pk(dc * e.z, dc * e.w);
    xd[off] = u0;
    xd[off + 1] = u1;
    uint4 s0, s1;
    s0.x = pk(wl * a.x, wl * a.y);  s0.y = pk(wl * a.z, wl * a.w);
    s0.z = pk(wl * b.x, wl * b.y);  s0.w = pk(wl * b.z, wl * b.w);
    s1.x = pk(wl * d.x, wl * d.y);  s1.y = pk(wl * d.z, wl * d.w);
    s1.z = pk(wl * e.x, wl * e.y);  s1.w = pk(wl * e.z, wl * e.w);
    z[off] = s0;
    z[off + 1] = s1;
}

// acc.x += f16_lo(raw); acc.y += f16_hi(raw)   (fp32 FMA with inline 1.0)
__device__ __forceinline__ void accmix(float& ax, float& ay, unsigned raw) {
    asm volatile(
        "v_fma_mix_f32 %0, 1.0, %2, %0 op_sel:[0,0,0] op_sel_hi:[0,1,0]\n\t"
        "v_fma_mix_f32 %1, 1.0, %2, %1 op_sel:[0,1,0] op_sel_hi:[0,1,0]"
        : "+v"(ax), "+v"(ay)
        : "v"(raw));
}

// acc.x += w * f16_lo(raw); acc.y += w * f16_hi(raw)
__device__ __forceinline__ void fmamix2(float& ax, float& ay, float w,
                                        unsigned raw) {
    asm volatile(
        "v_fma_mix_f32 %0, %2, %3, %0 op_sel:[0,0,0] op_sel_hi:[0,1,0]\n\t"
        "v_fma_mix_f32 %1, %2, %3, %1 op_sel:[0,1,0] op_sel_hi:[0,1,0]"
        : "+v"(ax), "+v"(ay)
        : "v"(w), "v"(raw));
}

#define ACC8(b, V)                          \
    accmix(acc[b + 0], acc[b + 1], (V).x);  \
    accmix(acc[b + 2], acc[b + 3], (V).y);  \
    accmix(acc[b + 4], acc[b + 5], (V).z);  \
    accmix(acc[b + 6], acc[b + 7], (V).w)

// Thread = (dest c, slab g). s = z[c] + sum_{src in in(c)} z[src] (16 feats,
// fp32 acc). Then z_new = dinv^2*s + wj*xd (fp16) or, last round,
// out = dinv*s + w0*x (fp32).
__global__ __launch_bounds__(256) void prop_kernel(
    const uint4* __restrict__ z_old, uint4* __restrict__ z_new,
    float* __restrict__ out, const uint4* __restrict__ xd,
    const float* __restrict__ x, const float* __restrict__ dinv,
    const int* __restrict__ offs, const int* __restrict__ edges,
    const float* __restrict__ wts, int j, int last, int N) {
    const int g = blockIdx.x & 7;
    const int c = (blockIdx.x >> 3) * blockDim.x + threadIdx.x;
    if (c >= N) return;
    const uint4* zs = z_old + (size_t)g * N * 2;  // this XCD's slab

    float acc[16];
#pragma unroll
    for (int i = 0; i < 16; ++i) acc[i] = 0.0f;

    // self loop term
    {
        uint4 v0 = zs[(size_t)c * 2];
        uint4 v1 = zs[(size_t)c * 2 + 1];
        ACC8(0, v0);
        ACC8(8, v1);
    }

    int e = offs[c];
    const int end = offs[c + 1];
    for (; e + 2 <= end; e += 2) {
        int s0 = __builtin_nontemporal_load(&edges[e]);
        int s1 = __builtin_nontemporal_load(&edges[e + 1]);
        uint4 a0 = zs[(size_t)s0 * 2];
        uint4 a1 = zs[(size_t)s0 * 2 + 1];
        uint4 b0 = zs[(size_t)s1 * 2];
        uint4 b1 = zs[(size_t)s1 * 2 + 1];
        ACC8(0, a0);
        ACC8(8, a1);
        ACC8(0, b0);
        ACC8(8, b1);
    }
    if (e < end) {
        int s0 = __builtin_nontemporal_load(&edges[e]);
        uint4 a0 = zs[(size_t)s0 * 2];
        uint4 a1 = zs[(size_t)s0 * 2 + 1];
        ACC8(0, a0);
        ACC8(8, a1);
    }

    const float dc = dinv[c];
    if (last) {
        const float w0 = wts[0];
        const float4* xr = (const float4*)(x + (size_t)c * F + g * 16);
        float4* orow = (float4*)(out + (size_t)c * F + g * 16);
#pragma unroll
        for (int u = 0; u < 4; ++u) {
            float4 xv = xr[u];
            float4 o;
            o.x = fmaf(dc, acc[u * 4 + 0], w0 * xv.x);
            o.y = fmaf(dc, acc[u * 4 + 1], w0 * xv.y);
            o.z = fmaf(dc, acc[u * 4 + 2], w0 * xv.z);
            o.w = fmaf(dc, acc[u * 4 + 3], w0 * xv.w);
            orow[u] = o;
        }
    } else {
        const float dc2 = dc * dc;
        const float wj = wts[j];
        size_t off = ((size_t)g * N + c) * 2;
        uint4 x0 = xd[off];
        uint4 x1 = xd[off + 1];
#pragma unroll
        for (int i = 0; i < 16; ++i) acc[i] *= dc2;
        fmamix2(acc[0], acc[1], wj, x0.x);
        fmamix2(acc[2], acc[3], wj, x0.y);
        fmamix2(acc[4], acc[5], wj, x0.z);
        fmamix2(acc[6], acc[7], wj, x0.w);
        fmamix2(acc[8], acc[9], wj, x1.x);
        fmamix2(acc[10], acc[11], wj, x1.y);
        fmamix2(acc[12], acc[13], wj, x1.z);
        fmamix2(acc[14], acc[15], wj, x1.w);
        uint4 o0, o1;
        o0.x = pk(acc[0], acc[1]);   o0.y = pk(acc[2], acc[3]);
        o0.z = pk(acc[4], acc[5]);   o0.w = pk(acc[6], acc[7]);
        o1.x = pk(acc[8], acc[9]);   o1.y = pk(acc[10], acc[11]);
        o1.z = pk(acc[12], acc[13]); o1.w = pk(acc[14], acc[15]);
        uint4* zn = z_new + off;
        zn[0] = o0;
        zn[1] = o1;
    }
}

extern "C" void kernel_launch(void* const* d_in, const int* in_sizes, int n_in,
                              void* d_out, int out_size, void* d_ws, size_t ws_size,
                              hipStream_t stream) {
    const float* x = (const float*)d_in[0];
    const int* ei = (const int*)d_in[1];
    const float* wts = (const float*)d_in[2];
    float* out = (float*)d_out;

    const int NF = in_sizes[0];
    const int N = NF / F;              // 100000
    const int E = in_sizes[1] / 2;     // 1600000
    const int order = in_sizes[2] - 1; // 10

    char* p = (char*)d_ws;
    auto carve = [&](size_t bytes) {
        void* q = (void*)p;
        p += (bytes + 255) & ~(size_t)255;
        return q;
    };
    int nb = (N + SCAN_B - 1) / SCAN_B;
    int*   cnt   = (int*)carve(sizeof(int) * (size_t)N);  // reused as cursor
    int*   offs  = (int*)carve(sizeof(int) * (size_t)(N + 1));
    int*   bsums = (int*)carve(sizeof(int) * (size_t)nb);
    float* dinv  = (float*)carve(sizeof(float) * (size_t)N);
    int*   edges = (int*)carve(4ull * (size_t)E);
    uint4* xd    = (uint4*)carve(32ull * (size_t)N * 8);  // 8 slabs x N x 16 half
    uint4* zA    = (uint4*)carve(32ull * (size_t)N * 8);
    uint4* zB    = (uint4*)carve(32ull * (size_t)N * 8);
    int*   cursor = cnt;  // cnt dead after scan1
    (void)ws_size;

    // ---- CSR build + normalization ----
    hipMemsetAsync(cnt, 0, sizeof(int) * (size_t)N, stream);
    count_kernel<<<(E + 255) / 256, 256, 0, stream>>>(ei, E, cnt);
    scan1_kernel<<<nb, SCAN_B, 0, stream>>>(cnt, offs, bsums, dinv, N);
    scan2_kernel<<<1, SCAN_B, 0, stream>>>(bsums, nb);
    scan3_kernel<<<(N + 1 + 255) / 256, 256, 0, stream>>>(offs, bsums, cursor, N, E);
    place_kernel<<<2048, 256, 0, stream>>>(ei, E, cursor, edges, N);

    const int nch = (N + 255) / 256;
    const int grid = nch * 8;

    // ---- seed: xd = dinv.*x, z = w[order]*xd (slab layout) ----
    conv_kernel<<<grid, 256, 0, stream>>>(x, dinv, xd, zA, wts, order, N);

    // ---- 10 Horner rounds on z: s = (A+I)z; z' = dinv^2 s + wj xd ----
    const uint4* zin = zA;
    uint4* zout = zB;
    for (int j = order - 1; j >= 0; --j) {
        int last = (j == 0);
        prop_kernel<<<grid, 256, 0, stream>>>(zin, zout, out, xd, x, dinv,
                                              offs, edges, wts, j, last, N);
        zin = zout;
        zout = (zout == zA) ? zB : zA;
    }
}